// Round 1
// baseline (224.631 us; speedup 1.0000x reference)
//
#include <hip/hip_runtime.h>
#include <cstdint>

#define BN_EPS 1e-5f

// dims
static constexpr int NB = 8192;
static constexpr int XH = 24, XW = 54;          // input 24x54
static constexpr int H1 = 11, W1 = 26;          // conv1 out (stride 2, VALID)
static constexpr int H2 = 5,  W2 = 12;          // conv2 out
static constexpr int KWORDS = 128;              // packed h2 words per sample (2 per channel: 60 bits -> 32+28)
static constexpr int JLIN = 500, JPAD = 512;
static constexpr int OWORDS = 16;               // packed h3 words per sample (500 bits -> 16 words)

// ---------------------------------------------------------------------------
// Kernel A: pack weight sign bits + precompute BN affine constants
// bnc layout: [0..31] inv1, [32..63] sh1, [64..127] inv2, [128..191] sh2
// ---------------------------------------------------------------------------
__global__ void pack_kernel(const float* __restrict__ conv1_w,
                            const float* __restrict__ conv2_w,
                            const float* __restrict__ lin_w,
                            const float* __restrict__ out_w,
                            const float* __restrict__ bn1_g, const float* __restrict__ bn1_b,
                            const float* __restrict__ bn1_m, const float* __restrict__ bn1_v,
                            const float* __restrict__ bn2_g, const float* __restrict__ bn2_b,
                            const float* __restrict__ bn2_m, const float* __restrict__ bn2_v,
                            uint32_t* __restrict__ w1p, uint32_t* __restrict__ m2,
                            uint32_t* __restrict__ wlin, uint32_t* __restrict__ wout,
                            float* __restrict__ bnc)
{
    const int N_WLIN = JPAD * KWORDS;   // 65536
    const int N_M2   = 64 * 9;          // 576
    const int N_WOUT = 10 * OWORDS;     // 160
    const int N_W1P  = 32;
    const int N_BN   = 96;
    const int TOT = N_WLIN + N_M2 + N_WOUT + N_W1P + N_BN;
    int stride = gridDim.x * blockDim.x;
    for (int i = blockIdx.x * blockDim.x + threadIdx.x; i < TOT; i += stride) {
        if (i < N_WLIN) {
            // lin mask word: j = row, k = word. word k=2c+hi covers flat f = c*60 + hi*32 + b
            int j = i >> 7, k = i & 127;
            uint32_t w = 0;
            if (j < JLIN) {
                int c = k >> 1, hi = k & 1;
                int nb = hi ? 28 : 32;
                const float* src = lin_w + (size_t)j * 3840 + c * 60 + hi * 32;
                for (int b = 0; b < nb; ++b)
                    w |= (src[b] > 0.0f ? 1u : 0u) << b;
            }
            wlin[i] = w;
        } else if (i < N_WLIN + N_M2) {
            int t = i - N_WLIN;
            int c = t / 9, tap = t % 9;
            uint32_t w = 0;
            for (int ic = 0; ic < 32; ++ic)
                w |= (conv2_w[c * 288 + ic * 9 + tap] > 0.0f ? 1u : 0u) << ic;
            m2[t] = w;
        } else if (i < N_WLIN + N_M2 + N_WOUT) {
            int t = i - N_WLIN - N_M2;
            int j = t >> 4, k = t & 15;
            uint32_t w = 0;
            for (int b = 0; b < 32; ++b) {
                int idx = k * 32 + b;
                if (idx < JLIN) w |= (out_w[j * 500 + idx] > 0.0f ? 1u : 0u) << b;
            }
            wout[t] = w;
        } else if (i < N_WLIN + N_M2 + N_WOUT + N_W1P) {
            int c = i - (N_WLIN + N_M2 + N_WOUT);
            uint32_t w = 0;
            for (int t = 0; t < 9; ++t)
                w |= (conv1_w[c * 9 + t] < 0.0f ? 1u : 0u) << t;  // bit=1 means negative weight
            w1p[c] = w;
        } else {
            int c = i - (N_WLIN + N_M2 + N_WOUT + N_W1P);
            if (c < 32) {
                float inv = bn1_g[c] / sqrtf(bn1_v[c] + BN_EPS);
                bnc[c]      = inv;
                bnc[32 + c] = bn1_b[c] - bn1_m[c] * inv;
            } else {
                int d = c - 32;
                float inv = bn2_g[d] / sqrtf(bn2_v[d] + BN_EPS);
                bnc[64 + d]  = inv;
                bnc[128 + d] = bn2_b[d] - bn2_m[d] * inv;
            }
        }
    }
}

// ---------------------------------------------------------------------------
// Kernel BC: fused conv1(+bn+relu+sign, packed along channel) -> LDS ->
//            conv2(+bn+relu+sign) -> packed h2b[sample][128 words]
// 4 samples per block, 256 threads.
// ---------------------------------------------------------------------------
__global__ __launch_bounds__(256) void conv_kernel(
    const float* __restrict__ x,
    const float* __restrict__ conv1_b, const float* __restrict__ conv2_b,
    const uint32_t* __restrict__ w1p, const uint32_t* __restrict__ m2,
    const float* __restrict__ bnc,
    uint32_t* __restrict__ h2b)
{
    __shared__ uint32_t s_in[4][288];   // packed conv1 output bits (32 channels/word), 286 positions
    __shared__ uint32_t s_base[4][60];  // per-position sum of popcounts over 9 taps

    int tid = threadIdx.x;
    int s0  = blockIdx.x * 4;

    // --- conv1: one packed u32 per (sample, oy, ox) ---
    for (int i = tid; i < 4 * 286; i += 256) {
        int sl = i / 286, p = i % 286;
        int oy = p / 26, ox = p % 26;
        const float* xs = x + (size_t)(s0 + sl) * (XH * XW);
        uint32_t px = 0;
        int t = 0;
        #pragma unroll
        for (int ky = 0; ky < 3; ++ky)
            #pragma unroll
            for (int kx = 0; kx < 3; ++kx) {
                float v = xs[(2 * oy + ky) * XW + (2 * ox + kx)];
                px |= (v < 0.0f ? 1u : 0u) << t;
                ++t;
            }
        uint32_t word = 0;
        #pragma unroll
        for (int c = 0; c < 32; ++c) {
            int d = 9 - 2 * __popc(px ^ w1p[c]);
            float z = __fadd_rn((float)d, conv1_b[c]);
            z = __fadd_rn(__fmul_rn(z, bnc[c]), bnc[32 + c]);
            word |= (z > 0.0f ? 1u : 0u) << c;
        }
        s_in[sl][p] = word;
    }
    __syncthreads();

    // --- base popcounts per output position ---
    for (int i = tid; i < 4 * 60; i += 256) {
        int sl = i / 60, p = i % 60;
        int oy = p / 12, ox = p % 12;
        uint32_t sum = 0;
        #pragma unroll
        for (int ky = 0; ky < 3; ++ky)
            #pragma unroll
            for (int kx = 0; kx < 3; ++kx)
                sum += __popc(s_in[sl][(2 * oy + ky) * 26 + (2 * ox + kx)]);
        s_base[sl][p] = sum;
    }
    __syncthreads();

    // --- conv2: thread = (sample_local, out_channel) ---
    int sl = tid >> 6;
    int c  = tid & 63;
    uint32_t m[9];
    #pragma unroll
    for (int t = 0; t < 9; ++t) m[t] = m2[c * 9 + t];
    float b2  = conv2_b[c];
    float inv = bnc[64 + c];
    float sh  = bnc[128 + c];

    uint32_t w0 = 0, w1 = 0;
    int r = 0;
    for (int oy = 0; oy < 5; ++oy) {
        for (int ox = 0; ox < 12; ++ox) {
            uint32_t acc = 0;
            #pragma unroll
            for (int ky = 0; ky < 3; ++ky)
                #pragma unroll
                for (int kx = 0; kx < 3; ++kx)
                    acc += __popc(s_in[sl][(2 * oy + ky) * 26 + (2 * ox + kx)] & m[ky * 3 + kx]);
            int conv = 2 * (int)acc - (int)s_base[sl][r];
            float z = __fadd_rn((float)conv, b2);
            z = __fadd_rn(__fmul_rn(z, inv), sh);
            uint32_t bit = (z > 0.0f) ? 1u : 0u;
            if (r < 32) w0 |= bit << r; else w1 |= bit << (r - 32);
            ++r;
        }
    }
    // word layout: k = 2c (+ r in [0,32)), 2c+1 (+ r-32 in [0,28)); top 4 bits of odd word are 0
    uint2* dst = (uint2*)(h2b + (size_t)(s0 + sl) * KWORDS + 2 * c);
    *dst = make_uint2(w0, w1);
}

// ---------------------------------------------------------------------------
// Kernel D: lin layer (500x3840 binarized GEMV batch) + relu + sign -> h3b bits
// block = 256 threads (32 jt x 8 st), 16 samples/block, 4 j-tiles of 128.
// thread register tile: 4 j (j = jbase + q*32 + jt) x 2 samples.
// ---------------------------------------------------------------------------
__global__ __launch_bounds__(256) void lin_kernel(
    const uint32_t* __restrict__ h2b,
    const uint32_t* __restrict__ wlin,
    const float* __restrict__ lin_b,
    uint32_t* __restrict__ h3b)
{
    __shared__ uint32_t s_msk[128 * 129];  // 64.5 KB, stride 129 -> conflict-free (bank = jt+k)
    __shared__ uint32_t s_in[16 * 129];    // 8.1 KB
    __shared__ int      s_B[16];
    __shared__ uint32_t s_out[16 * 16];    // h3 bit accumulation

    int tid = threadIdx.x;
    int s0  = blockIdx.x * 16;

    for (int i = tid; i < 16 * 128; i += 256) {
        int s = i >> 7, k = i & 127;
        s_in[s * 129 + k] = h2b[(size_t)(s0 + s) * KWORDS + k];
    }
    s_out[tid] = 0;   // 16*16 == 256
    __syncthreads();
    if (tid < 16) {
        int b = 0;
        for (int k = 0; k < 128; ++k) b += __popc(s_in[tid * 129 + k]);
        s_B[tid] = b;
    }
    __syncthreads();

    int jt = tid & 31, st = tid >> 5;
    const uint32_t* in0 = s_in + (st * 2) * 129;
    const uint32_t* in1 = s_in + (st * 2 + 1) * 129;
    const uint32_t* mp  = s_msk + jt * 129;

    for (int tile = 0; tile < 4; ++tile) {
        int jbase = tile * 128;
        for (int i = tid; i < 128 * 128; i += 256) {
            int row = i >> 7, col = i & 127;
            s_msk[row * 129 + col] = wlin[(size_t)(jbase + row) * KWORDS + col];
        }
        __syncthreads();

        int P[4][2] = {};
        for (int k = 0; k < 128; ++k) {
            uint32_t a0 = in0[k], a1 = in1[k];
            #pragma unroll
            for (int q = 0; q < 4; ++q) {
                uint32_t mm = mp[(q * 32) * 129 + k];
                P[q][0] += __popc(mm & a0);
                P[q][1] += __popc(mm & a1);
            }
        }
        #pragma unroll
        for (int q = 0; q < 4; ++q) {
            int j = jbase + q * 32 + jt;
            if (j < JLIN) {
                float lb = lin_b[j];
                #pragma unroll
                for (int ss = 0; ss < 2; ++ss) {
                    int s = st * 2 + ss;
                    float z = __fadd_rn((float)(2 * P[q][ss] - s_B[s]), lb);
                    if (z > 0.0f)
                        atomicOr(&s_out[s * 16 + (j >> 5)], 1u << (j & 31));
                }
            }
        }
        __syncthreads();
    }

    {
        int s = tid >> 4, k = tid & 15;
        h3b[(size_t)(s0 + s) * OWORDS + k] = s_out[tid];
    }
}

// ---------------------------------------------------------------------------
// Kernel E: out layer (10x500 binarized) -> f32 logits
// ---------------------------------------------------------------------------
__global__ __launch_bounds__(256) void out_kernel(
    const uint32_t* __restrict__ h3b,
    const uint32_t* __restrict__ wout,
    const float* __restrict__ out_b,
    float* __restrict__ out)
{
    int idx = blockIdx.x * blockDim.x + threadIdx.x;
    if (idx >= NB * 10) return;
    int s = idx / 10, o = idx % 10;
    const uint32_t* in = h3b + (size_t)s * OWORDS;
    const uint32_t* mo = wout + o * OWORDS;
    int P = 0, B = 0;
    #pragma unroll
    for (int k = 0; k < OWORDS; ++k) {
        uint32_t a = in[k];
        P += __popc(a & mo[k]);
        B += __popc(a);
    }
    out[idx] = __fadd_rn((float)(2 * P - B), out_b[o]);
}

// ---------------------------------------------------------------------------
extern "C" void kernel_launch(void* const* d_in, const int* in_sizes, int n_in,
                              void* d_out, int out_size, void* d_ws, size_t ws_size,
                              hipStream_t stream)
{
    const float* x       = (const float*)d_in[0];
    const float* conv1_w = (const float*)d_in[1];
    const float* conv1_b = (const float*)d_in[2];
    const float* bn1_g   = (const float*)d_in[3];
    const float* bn1_b   = (const float*)d_in[4];
    const float* bn1_m   = (const float*)d_in[5];
    const float* bn1_v   = (const float*)d_in[6];
    const float* conv2_w = (const float*)d_in[7];
    const float* conv2_b = (const float*)d_in[8];
    const float* bn2_g   = (const float*)d_in[9];
    const float* bn2_b   = (const float*)d_in[10];
    const float* bn2_m   = (const float*)d_in[11];
    const float* bn2_v   = (const float*)d_in[12];
    const float* lin_w   = (const float*)d_in[13];
    const float* lin_b   = (const float*)d_in[14];
    const float* out_w   = (const float*)d_in[15];
    const float* out_b   = (const float*)d_in[16];

    char* ws = (char*)d_ws;
    uint32_t* h2b  = (uint32_t*)(ws + 0);                 // 8192*128*4 = 4,194,304
    uint32_t* h3b  = (uint32_t*)(ws + 4194304);           // 8192*16*4  =   524,288
    uint32_t* wlin = (uint32_t*)(ws + 4718592);           // 512*128*4  =   262,144
    uint32_t* m2   = (uint32_t*)(ws + 4980736);           // 576*4      =     2,304
    uint32_t* w1p  = (uint32_t*)(ws + 4983040);           // 32*4       =       128
    uint32_t* wout = (uint32_t*)(ws + 4983296);           // 160*4      =       640 (256-aligned start)
    float*    bnc  = (float*)   (ws + 4984064);           // 192*4      =       768

    pack_kernel<<<260, 256, 0, stream>>>(conv1_w, conv2_w, lin_w, out_w,
                                         bn1_g, bn1_b, bn1_m, bn1_v,
                                         bn2_g, bn2_b, bn2_m, bn2_v,
                                         w1p, m2, wlin, wout, bnc);
    conv_kernel<<<NB / 4, 256, 0, stream>>>(x, conv1_b, conv2_b, w1p, m2, bnc, h2b);
    lin_kernel<<<NB / 16, 256, 0, stream>>>(h2b, wlin, lin_b, h3b);
    out_kernel<<<(NB * 10 + 255) / 256, 256, 0, stream>>>(h3b, wout, out_b, (float*)d_out);
}